// Round 4
// baseline (150.409 us; speedup 1.0000x reference)
//
#include <hip/hip_runtime.h>
#include <hip/hip_cooperative_groups.h>
#include <math.h>

namespace cg = cooperative_groups;

#define B_ 1000
#define D_ 8
#define PRE_ 98
#define NXT_ 2048
#define J_ 32
#define K_ 64
#define A_ 5

typedef __attribute__((ext_vector_type(8))) __bf16 bf16x8;
typedef __attribute__((ext_vector_type(4))) float f32x4;
typedef __attribute__((ext_vector_type(16))) float f32x16;
typedef __attribute__((ext_vector_type(8))) unsigned short us8;

__device__ __forceinline__ unsigned short f2bf(float f) {
  union { float f; unsigned u; } v;
  v.f = f;
  unsigned r = v.u + 0x7fffu + ((v.u >> 16) & 1u);
  return (unsigned short)(r >> 16);
}

__device__ __forceinline__ unsigned cvtpk(float lo, float hi) {
  unsigned r;
  asm("v_cvt_pk_bf16_f32 %0, %1, %2" : "=v"(r) : "v"(lo), "v"(hi));
  return r;
}

__device__ __forceinline__ void gload16(const void* g, void* l) {
  __builtin_amdgcn_global_load_lds(
      (const __attribute__((address_space(1))) void*)g,
      (__attribute__((address_space(3))) void*)l, 16, 0, 0);
}

// ws layout (float offsets):
//   [0, 524288)         S1part[oc2(2)][1024][8][32] f32
//   [524288, 1572864)   w1sw [8][2048 rows][256B swizzled] bf16 (k=98 -> b1)
//   [1572864, 1835008)  wcarr[8][8192 chunks][8] bf16 (fragment-linear)
//   [1835008, +1024)    spsum  (slot = d*128 + m*4 + wave)
//   [1836032, +1024)    spsq
//   [1837056, +256)     wcsum[d*32+j]

#define W3S 33
#define W4S 99

struct PhaseC {
  float W3l[98 * W3S];
  float W4l[49 * W4S];
  float Wol[490];
  float b3l[98], b4l[49], bol[10];
  float cutl[32], coefl[256], konstl[32];
  float mvals[8], vvals[8], gmgv[2];
  float offs[D_][J_];
  float h1[4][32], h2[4][100], h3[4][52], lg[4][10], lsel[4];
};

__global__ __launch_bounds__(256) void fused(
    const float* __restrict__ x, const float* __restrict__ W1,
    const float* __restrict__ b1, const float* __restrict__ Wc,
    const float* __restrict__ bc, const float* __restrict__ b_mat,
    const float* __restrict__ h_mat, const float* __restrict__ a_mat,
    const float* __restrict__ noise, const float* __restrict__ indicator,
    const float* __restrict__ cutb, const float* __restrict__ W3,
    const float* __restrict__ b3, const float* __restrict__ W4,
    const float* __restrict__ b4, const float* __restrict__ Wo,
    const float* __restrict__ bo, unsigned short* __restrict__ w1sw,
    unsigned short* __restrict__ wcarr, float* __restrict__ S1part,
    float* __restrict__ spsum, float* __restrict__ spsq,
    float* __restrict__ wcsum, float* __restrict__ out) {
  __shared__ __align__(16) char smem[49152];

  const int id = blockIdx.x;
  const int d = id & 7;     // XCD-pinned device index (perf heuristic only)
  const int m = id >> 3;    // 0..31
  const int tid = threadIdx.x;

  // ================= phase A: weight conversion =================
  {
    // W1 (+bias as k=98 column), rows m*64 .. m*64+63 of device d
#pragma unroll
    for (int c = 0; c < 4; ++c) {
      int g = m * 1024 + tid * 4 + c;  // chunk index within d, [0, 32768)
      int row = g >> 4, t = g & 15;
      int k0 = (t ^ (row & 7)) * 8;
      const float* src = W1 + ((size_t)d * 2048 + row) * 98;
      float bias = b1[d * 2048 + row];
      us8 v;
#pragma unroll
      for (int e = 0; e < 8; ++e) {
        int k = k0 + e;
        float f = (k < 98) ? src[k] : ((k == 98) ? bias : 0.0f);
        v[e] = f2bf(f);
      }
      *(us8*)(w1sw + ((size_t)d * 32768 + g) * 8) = v;
    }
    // Wc fragment-linear
    {
      int g = m * 256 + tid;  // [0, 8192) per d
      int oc = g >> 11, rem = g & 2047;
      int ot = rem >> 8, t = (rem >> 6) & 3, l = g & 63;
      int j = l & 31;
      int o = oc * 512 + ot * 64 + t * 16 + (l >> 5) * 8;
      const float* src = Wc + ((size_t)d * J_ + j) * NXT_ + o;
      us8 v;
#pragma unroll
      for (int e = 0; e < 8; ++e) v[e] = f2bf(src[e]);
      *(us8*)(wcarr + ((size_t)d * 8192 + g) * 8) = v;
    }
    // wcsum for (d, j=m): full sum over 2048 o
    {
      const float* p = Wc + ((size_t)d * J_ + m) * NXT_;
      float s = 0.0f;
#pragma unroll
      for (int i = 0; i < 8; ++i) s += p[tid * 8 + i];
      float* red = (float*)smem;
      red[tid] = s;
      __syncthreads();
      for (int st = 128; st; st >>= 1) {
        if (tid < st) red[tid] += red[tid + st];
        __syncthreads();
      }
      if (tid == 0) wcsum[d * J_ + m] = red[0];
    }
  }
  __threadfence();
  cg::this_grid().sync();

  // ================= phase B: fused double-GEMM =================
  {
    const int bt = m >> 1, oc2 = m & 1;
    const int wave = tid >> 6, lane = tid & 63;
    const int oh = wave >> 1, bh = wave & 1;
    const int l31 = lane & 31, hi = lane >> 5;
    const bool lo_half = (hi == 0);

    const unsigned short* w1g = w1sw + ((size_t)d * 2048 + oc2 * 1024) * 128;
    const unsigned short* wcg = wcarr + ((size_t)d * 32 + oc2 * 16) * 2048;

    // stage W1 tile 0 into buffer 0
#pragma unroll
    for (int i = 0; i < 4; ++i) {
      int c = wave * 4 + i;
      gload16(w1g + c * 512 + lane * 8, smem + c * 1024);
    }
    // convert this block's exclusive x tile f32 -> bf16 swizzled LDS @32768
    {
      const int xrow = tid >> 2, t4 = tid & 3;  // 64 rows x 4 threads
      const int gb = bt * 64 + xrow;
      char* xr = smem + 32768 + xrow * 256;
      const float* src = x + (size_t)gb * (D_ * PRE_) + d * 98;
#pragma unroll
      for (int c = t4 * 4; c < t4 * 4 + 4; ++c) {
        us8 v;
#pragma unroll
        for (int e = 0; e < 8; ++e) {
          int k = c * 8 + e;
          float f = 0.0f;
          if (gb < B_) f = (k < 98) ? src[k] : ((k == 98) ? 1.0f : 0.0f);
          v[e] = f2bf(f);
        }
        *(us8*)(xr + ((c ^ (xrow & 7)) * 16)) = v;
      }
    }
    __syncthreads();

    // x fragments -> registers (reused across all 16 o-tiles)
    const int rb = bh * 32 + l31;
    const int keyB = (rb & 7) << 4;
    bf16x8 xf[8];
#pragma unroll
    for (int ks = 0; ks < 8; ++ks)
      xf[ks] = *(const bf16x8*)(smem + 32768 + rb * 256 +
                                ((ks * 32 + hi * 16) ^ keyB));

    const int ra = oh * 32 + l31;
    const int keyA = (ra & 7) << 4;

    f32x16 acc2 = {};
    float lsum = 0.0f, lsq = 0.0f;

    for (int tt = 0; tt < 16; ++tt) {
      const char* wbuf = smem + (tt & 1) * 16384;
      if (tt < 15) {  // early-issue next W1 tile into other buffer
        const unsigned short* src = w1g + (size_t)(tt + 1) * 8192;
        char* dst = smem + ((tt + 1) & 1) * 16384;
#pragma unroll
        for (int i = 0; i < 4; ++i) {
          int c = wave * 4 + i;
          gload16(src + c * 512 + lane * 8, dst + c * 1024);
        }
      }
      const unsigned short* wct = wcg + (size_t)tt * 2048 + oh * 1024 + lane * 8;
      bf16x8 wc0 = *(const bf16x8*)(wct);
      bf16x8 wc1 = *(const bf16x8*)(wct + 512);

      // GEMM1: 32x32 quadrant (oh, bh), K=128
      f32x16 acc = {};
#pragma unroll
      for (int ks = 0; ks < 8; ++ks) {
        bf16x8 a = *(const bf16x8*)(wbuf + ra * 256 +
                                    ((ks * 32 + hi * 16) ^ keyA));
        acc = __builtin_amdgcn_mfma_f32_32x32x16_bf16(a, xf[ks], acc, 0, 0, 0);
      }

      // epilogue: relu + stats, in-register P fragments (no LDS round-trip)
      float v[16];
#pragma unroll
      for (int r = 0; r < 16; ++r) {
        v[r] = fmaxf(acc[r], 0.0f);
        lsum += v[r];
        lsq = fmaf(v[r], v[r], lsq);
      }
#pragma unroll
      for (int t = 0; t < 2; ++t) {
        unsigned A0 = cvtpk(v[8 * t + 0], v[8 * t + 1]);
        unsigned A1 = cvtpk(v[8 * t + 2], v[8 * t + 3]);
        unsigned B0 = cvtpk(v[8 * t + 4], v[8 * t + 5]);
        unsigned B1 = cvtpk(v[8 * t + 6], v[8 * t + 7]);
        unsigned sA0 = __shfl_xor(A0, 32);
        unsigned sA1 = __shfl_xor(A1, 32);
        unsigned sB0 = __shfl_xor(B0, 32);
        unsigned sB1 = __shfl_xor(B1, 32);
        union { unsigned u[4]; bf16x8 v; } f;
        f.u[0] = lo_half ? A0 : sB0;
        f.u[1] = lo_half ? A1 : sB1;
        f.u[2] = lo_half ? sA0 : B0;
        f.u[3] = lo_half ? sA1 : B1;
        acc2 = __builtin_amdgcn_mfma_f32_32x32x16_bf16(t == 0 ? wc0 : wc1, f.v,
                                                       acc2, 0, 0, 0);
      }
      __syncthreads();  // drains prefetch; gates buffer reuse
    }

    // cross-wave oh-pair reduction (x region is dead -> scratch)
    if (oh == 1) {
      char* rbase = smem + 32768 + bh * 5120 + lane * 80;
#pragma unroll
      for (int g = 0; g < 4; ++g) {
        f32x4 q = {acc2[4 * g + 0], acc2[4 * g + 1], acc2[4 * g + 2],
                   acc2[4 * g + 3]};
        *(f32x4*)(rbase + g * 16) = q;
      }
    }
    __syncthreads();
    if (oh == 0) {
      const char* rbase = smem + 32768 + bh * 5120 + lane * 80;
      const int b = bt * 64 + bh * 32 + l31;
      float* s1b = S1part + (((size_t)oc2 * 1024 + b) * 8 + d) * 32;
#pragma unroll
      for (int g = 0; g < 4; ++g) {
        f32x4 p = *(const f32x4*)(rbase + g * 16);
        f32x4 q = {acc2[4 * g + 0] + p[0], acc2[4 * g + 1] + p[1],
                   acc2[4 * g + 2] + p[2], acc2[4 * g + 3] + p[3]};
        int j0 = 8 * g + 4 * hi;
        *(f32x4*)(s1b + j0) = q;
      }
    }

    // stats: per-wave shuffle reduction
#pragma unroll
    for (int off = 32; off; off >>= 1) {
      lsum += __shfl_down(lsum, off);
      lsq += __shfl_down(lsq, off);
    }
    if (lane == 0) {
      int slot = d * 128 + m * 4 + wave;
      spsum[slot] = lsum;
      spsq[slot] = lsq;
    }
  }
  __threadfence();
  cg::this_grid().sync();

  // ================= phase C: combine + tail MLP =================
  {
    PhaseC* C = (PhaseC*)smem;

    for (int idx = tid; idx < 98 * 32; idx += 256) {
      int o = idx >> 5, j = idx & 31;
      C->W3l[o * W3S + j] = W3[idx];
    }
    for (int idx = tid; idx < 49 * 98; idx += 256) {
      int o = idx / 98, k = idx - o * 98;
      C->W4l[o * W4S + k] = W4[idx];
    }
    for (int idx = tid; idx < 490; idx += 256) C->Wol[idx] = Wo[idx];
    if (tid < 98) C->b3l[tid] = b3[tid];
    if (tid < 49) C->b4l[tid] = b4[tid];
    if (tid < 10) C->bol[tid] = bo[tid];
    if (tid < 32) C->cutl[tid] = cutb[tid];

    // stats -> gm, inv
    if (tid < 8) {
      float s = 0.0f, q = 0.0f;
      for (int i = 0; i < 128; ++i) {
        s += spsum[tid * 128 + i];
        q += spsq[tid * 128 + i];
      }
      const float inv_cnt = 1.0f / ((float)B_ * (float)NXT_);
      float mn = s * inv_cnt;
      C->mvals[tid] = mn;
      C->vvals[tid] = q * inv_cnt - mn * mn;
    }
    __syncthreads();
    if (tid == 0) {
      float gm = 0.0f, gv = 0.0f;
      for (int dd = 0; dd < 8; ++dd) {
        gm += C->mvals[dd];
        gv += C->vvals[dd];
      }
      gm *= 0.125f;
      gv *= 0.125f;
      C->gmgv[0] = gm;
      C->gmgv[1] = 1.0f / sqrtf(gv + 1e-6f);
    }
    __syncthreads();
    {
      int dd = tid >> 5, j = tid & 31;
      float hs[A_] = {0, 0, 0, 0, 0};
      for (int k = 0; k < K_; ++k) {
        float indv = indicator[j * K_ + k];
        if (indv != 0.0f) {
          const float* hp = h_mat + ((size_t)dd * K_ + k) * A_;
#pragma unroll
          for (int a = 0; a < A_; ++a) hs[a] = fmaf(indv, hp[a], hs[a]);
        }
      }
      float hv = 0.0f;
#pragma unroll
      for (int a = 0; a < A_; ++a) hv = fmaf(hs[a], a_mat[j * A_ + a], hv);
      float c = b_mat[dd * J_ + j] * hv;
      float gm = C->gmgv[0], inv = C->gmgv[1];
      C->coefl[tid] = c * inv;
      C->offs[dd][j] = c * (bc[dd * J_ + j] - gm * wcsum[dd * J_ + j] * inv);
    }
    __syncthreads();
    if (tid < J_) {
      float nz = 0.0f;
#pragma unroll
      for (int a = 0; a < A_; ++a)
        nz = fmaf(a_mat[tid * A_ + a], noise[tid * A_ + a], nz);
      float s = nz;
#pragma unroll
      for (int dd = 0; dd < D_; ++dd) s += C->offs[dd][tid];
      C->konstl[tid] = s;
    }
    __syncthreads();

    if (id < 250) {
      const int row = tid >> 6, lane = tid & 63;
      const int b = id * 4 + row;

      if (lane < 32) {
        float rsum = C->konstl[lane];
#pragma unroll
        for (int dd = 0; dd < D_; ++dd) {
          float s = S1part[((size_t)b * 8 + dd) * 32 + lane] +
                    S1part[(((size_t)1024 + b) * 8 + dd) * 32 + lane];
          rsum = fmaf(C->coefl[dd * J_ + lane], s, rsum);
        }
        C->h1[row][lane] = fmaxf(rsum + C->cutl[lane], 0.0f);
      }
      __syncthreads();

      for (int o = lane; o < 98; o += 64) {
        float a = C->b3l[o];
#pragma unroll
        for (int j = 0; j < 32; ++j)
          a = fmaf(C->h1[row][j], C->W3l[o * W3S + j], a);
        C->h2[row][o] = fmaxf(a, 0.0f);
      }
      __syncthreads();

      if (lane < 49) {
        float a = C->b4l[lane];
        for (int k = 0; k < 98; ++k)
          a = fmaf(C->h2[row][k], C->W4l[lane * W4S + k], a);
        C->h3[row][lane] = fmaxf(a, 0.0f);
      }
      __syncthreads();

      if (lane < 10) {
        float a = C->bol[lane];
#pragma unroll
        for (int k = 0; k < 49; ++k)
          a = fmaf(C->h3[row][k], C->Wol[lane * 49 + k], a);
        C->lg[row][lane] = a;
      }
      __syncthreads();
      if (lane == 0) {
        float mx = C->lg[row][0];
        for (int i = 1; i < 10; ++i) mx = fmaxf(mx, C->lg[row][i]);
        float se = 0.0f;
        for (int i = 0; i < 10; ++i) se += expf(C->lg[row][i] - mx);
        C->lsel[row] = mx + logf(se);
      }
      __syncthreads();
      if (lane < 10) out[(size_t)b * 10 + lane] = C->lg[row][lane] - C->lsel[row];
    }
  }
}

extern "C" void kernel_launch(void* const* d_in, const int* in_sizes, int n_in,
                              void* d_out, int out_size, void* d_ws,
                              size_t ws_size, hipStream_t stream) {
  const float* x = (const float*)d_in[0];
  const float* W1 = (const float*)d_in[1];
  const float* b1 = (const float*)d_in[2];
  const float* Wc = (const float*)d_in[3];
  const float* bc = (const float*)d_in[4];
  const float* cutb = (const float*)d_in[5];
  const float* bmat = (const float*)d_in[6];
  const float* hmat = (const float*)d_in[7];
  const float* amat = (const float*)d_in[8];
  const float* noise = (const float*)d_in[9];
  const float* W3 = (const float*)d_in[10];
  const float* b3 = (const float*)d_in[11];
  const float* W4 = (const float*)d_in[12];
  const float* b4 = (const float*)d_in[13];
  const float* Wo = (const float*)d_in[14];
  const float* bo = (const float*)d_in[15];
  const float* ind = (const float*)d_in[16];

  float* ws = (float*)d_ws;
  float* S1part = ws;                                       // 524288 f
  unsigned short* w1sw = (unsigned short*)(ws + 524288);    // 2,097,152 us
  unsigned short* wcarr = (unsigned short*)(ws + 1572864);  // 524,288 us
  float* spsum = ws + 1835008;                              // 1024
  float* spsq = ws + 1836032;                               // 1024
  float* wcsum = ws + 1837056;                              // 256
  float* outp = (float*)d_out;

  void* args[] = {(void*)&x,     (void*)&W1,    (void*)&b1,    (void*)&Wc,
                  (void*)&bc,    (void*)&bmat,  (void*)&hmat,  (void*)&amat,
                  (void*)&noise, (void*)&ind,   (void*)&cutb,  (void*)&W3,
                  (void*)&b3,    (void*)&W4,    (void*)&b4,    (void*)&Wo,
                  (void*)&bo,    (void*)&w1sw,  (void*)&wcarr, (void*)&S1part,
                  (void*)&spsum, (void*)&spsq,  (void*)&wcsum, (void*)&outp};
  hipLaunchCooperativeKernel((void*)fused, dim3(256), dim3(256), args, 0,
                             stream);
}

// Round 5
// 54.390 us; speedup vs baseline: 2.7654x; 2.7654x over previous
//
#include <hip/hip_runtime.h>
#include <math.h>

#define B_ 1000
#define D_ 8
#define PRE_ 98
#define NXT_ 2048
#define J_ 32
#define K_ 64
#define A_ 5

typedef __attribute__((ext_vector_type(8))) __bf16 bf16x8;
typedef __attribute__((ext_vector_type(4))) float f32x4;
typedef __attribute__((ext_vector_type(16))) float f32x16;
typedef __attribute__((ext_vector_type(8))) unsigned short us8;

__device__ __forceinline__ unsigned short f2bf(float f) {
  union { float f; unsigned u; } v;
  v.f = f;
  unsigned r = v.u + 0x7fffu + ((v.u >> 16) & 1u);
  return (unsigned short)(r >> 16);
}

__device__ __forceinline__ unsigned cvtpk(float lo, float hi) {
  unsigned r;
  asm("v_cvt_pk_bf16_f32 %0, %1, %2" : "=v"(r) : "v"(lo), "v"(hi));
  return r;
}

// ws layout (float offsets):
//   [0, 1048576)        S1part[oc4(4)][1024 b][8 d][32 j] f32
//   [1048576, 2097152)  w1a: frag fi=((d*64+og)*8+ks), 64 lanes x 8 bf16
//                       lane: o=og*32+(lane&31), k=ks*16+(lane>>5)*8 (k=98 -> b1)
//   [2097152, 2621440)  xa:  frag fi=((d*32+bg)*8+ks), b=bg*32+(lane&31) (k=98 -> 1.0)
//   [2621440, 2883584)  wca: frag fi=((d*64+og)*2+t), j=lane&31, o=og*32+t*16+(lane>>5)*8
//   [2883584, +2048)    spsum  (slot = d*256 + rest*4 + wave)
//   [2885632, +2048)    spsq
//   [2887680, +256)     wcsum[d*32+j]

__global__ __launch_bounds__(256) void kcvt(
    const float* __restrict__ x, const float* __restrict__ W1,
    const float* __restrict__ b1, const float* __restrict__ Wc,
    unsigned short* __restrict__ w1a, unsigned short* __restrict__ xa,
    unsigned short* __restrict__ wca, float* __restrict__ wcsum) {
  const int bid = blockIdx.x, tid = threadIdx.x;
  if (bid < 1024) {  // W1 fragments (+bias as k=98)
    int chunk = bid * 256 + tid;  // [0, 262144)
    int lane = chunk & 63, ks = (chunk >> 6) & 7;
    int og = (chunk >> 9) & 63, d = chunk >> 15;
    int o = og * 32 + (lane & 31);
    int k0 = ks * 16 + (lane >> 5) * 8;
    const float* src = W1 + (size_t)(d * 2048 + o) * 98;
    float bias = b1[d * 2048 + o];
    us8 v;
#pragma unroll
    for (int e = 0; e < 8; ++e) {
      int k = k0 + e;
      float f = (k < 98) ? src[k] : ((k == 98) ? bias : 0.0f);
      v[e] = f2bf(f);
    }
    *(us8*)(w1a + (size_t)chunk * 8) = v;
  } else if (bid < 1536) {  // x fragments (+ones col; rows >= B_ all-zero)
    int chunk = (bid - 1024) * 256 + tid;  // [0, 131072)
    int lane = chunk & 63, ks = (chunk >> 6) & 7;
    int bg = (chunk >> 9) & 31, d = chunk >> 14;
    int b = bg * 32 + (lane & 31);
    int k0 = ks * 16 + (lane >> 5) * 8;
    us8 v;
    if (b < B_) {
      const float* src = x + (size_t)b * (D_ * PRE_) + d * 98;
#pragma unroll
      for (int e = 0; e < 8; ++e) {
        int k = k0 + e;
        float f = (k < 98) ? src[k] : ((k == 98) ? 1.0f : 0.0f);
        v[e] = f2bf(f);
      }
    } else {
#pragma unroll
      for (int e = 0; e < 8; ++e) v[e] = 0;
    }
    *(us8*)(xa + (size_t)chunk * 8) = v;
  } else if (bid < 1792) {  // Wc fragments
    int chunk = (bid - 1536) * 256 + tid;  // [0, 65536)
    int lane = chunk & 63, t = (chunk >> 6) & 1;
    int og = (chunk >> 7) & 63, d = chunk >> 13;
    int j = lane & 31;
    int o = og * 32 + t * 16 + (lane >> 5) * 8;
    const float* src = Wc + (size_t)(d * J_ + j) * NXT_ + o;
    us8 v;
#pragma unroll
    for (int e = 0; e < 8; ++e) v[e] = f2bf(src[e]);
    *(us8*)(wca + (size_t)chunk * 8) = v;
  } else {  // wcsum rows
    __shared__ float red[256];
    int dj = bid - 1792;
    const float* p = Wc + (size_t)dj * NXT_;
    float s = 0.0f;
    for (int i = tid; i < NXT_; i += 256) s += p[i];
    red[tid] = s;
    __syncthreads();
    for (int st = 128; st; st >>= 1) {
      if (tid < st) red[tid] += red[tid + st];
      __syncthreads();
    }
    if (tid == 0) wcsum[dj] = red[0];
  }
}

__global__ __launch_bounds__(256, 2) void k1_reg(
    const unsigned short* __restrict__ w1a, const unsigned short* __restrict__ xa,
    const unsigned short* __restrict__ wca, float* __restrict__ S1part,
    float* __restrict__ spsum, float* __restrict__ spsq) {
  // redbuf[(wavepair q)*16 + r][lane] transposed: conflict-free b32 access
  __shared__ float redbuf[96 * 65];  // 24.4 KB

  const int id = blockIdx.x;
  const int d = id & 7;          // XCD-pinned
  const int rest = id >> 3;      // 0..63
  const int bg2 = rest & 15, oc4 = rest >> 4;
  const int tid = threadIdx.x;
  const int w = tid >> 6, lane = tid & 63;
  const int l31 = lane & 31, hi = lane >> 5;
  const bool lo_half = (hi == 0);

  // x fragments for this wave's two b-groups (loaded once, reused 16x)
  bf16x8 xf0[8], xf1[8];
  {
    const unsigned short* xb0 =
        xa + ((size_t)(d * 32 + bg2 * 2 + 0) * 8) * 512 + lane * 8;
    const unsigned short* xb1 =
        xa + ((size_t)(d * 32 + bg2 * 2 + 1) * 8) * 512 + lane * 8;
#pragma unroll
    for (int ks = 0; ks < 8; ++ks) {
      xf0[ks] = *(const bf16x8*)(xb0 + ks * 512);
      xf1[ks] = *(const bf16x8*)(xb1 + ks * 512);
    }
  }

  const int og0 = oc4 * 16 + w * 4;
  const unsigned short* w1b =
      w1a + ((size_t)(d * 64 + og0) * 8) * 512 + lane * 8;
  const unsigned short* wcb =
      wca + ((size_t)(d * 64 + og0) * 2) * 512 + lane * 8;

  f32x16 acc2q[2] = {};
  float lsum = 0.0f, lsq = 0.0f;

#pragma unroll
  for (int u = 0; u < 4; ++u) {
    bf16x8 a[8];
#pragma unroll
    for (int ks = 0; ks < 8; ++ks)
      a[ks] = *(const bf16x8*)(w1b + (size_t)(u * 8 + ks) * 512);
    bf16x8 wc0 = *(const bf16x8*)(wcb + (size_t)(u * 2 + 0) * 512);
    bf16x8 wc1 = *(const bf16x8*)(wcb + (size_t)(u * 2 + 1) * 512);

    // GEMM1: two independent 32x32 accumulator chains share a[] (W1 reuse)
    f32x16 accg[2] = {};
#pragma unroll
    for (int ks = 0; ks < 8; ++ks) {
      accg[0] = __builtin_amdgcn_mfma_f32_32x32x16_bf16(a[ks], xf0[ks], accg[0], 0, 0, 0);
      accg[1] = __builtin_amdgcn_mfma_f32_32x32x16_bf16(a[ks], xf1[ks], accg[1], 0, 0, 0);
    }

    // epilogue per b-group: relu + stats + in-register P frags -> GEMM2
#pragma unroll
    for (int q = 0; q < 2; ++q) {
      float v[16];
#pragma unroll
      for (int r = 0; r < 16; ++r) {
        v[r] = fmaxf(accg[q][r], 0.0f);
        lsum += v[r];
        lsq = fmaf(v[r], v[r], lsq);
      }
#pragma unroll
      for (int t = 0; t < 2; ++t) {
        unsigned A0 = cvtpk(v[8 * t + 0], v[8 * t + 1]);
        unsigned A1 = cvtpk(v[8 * t + 2], v[8 * t + 3]);
        unsigned B0 = cvtpk(v[8 * t + 4], v[8 * t + 5]);
        unsigned B1 = cvtpk(v[8 * t + 6], v[8 * t + 7]);
        unsigned sA0 = __shfl_xor(A0, 32);
        unsigned sA1 = __shfl_xor(A1, 32);
        unsigned sB0 = __shfl_xor(B0, 32);
        unsigned sB1 = __shfl_xor(B1, 32);
        union { unsigned u[4]; bf16x8 v; } f;
        f.u[0] = lo_half ? A0 : sB0;
        f.u[1] = lo_half ? A1 : sB1;
        f.u[2] = lo_half ? sA0 : B0;
        f.u[3] = lo_half ? sA1 : B1;
        acc2q[q] = __builtin_amdgcn_mfma_f32_32x32x16_bf16(
            t == 0 ? wc0 : wc1, f.v, acc2q[q], 0, 0, 0);
      }
    }
  }

  // cross-wave reduction: waves 1..3 park acc2 in LDS (transposed rows,
  // lane-stride-1 => conflict-free), wave 0 sums and writes S1part slice.
  if (w > 0) {
#pragma unroll
    for (int q = 0; q < 2; ++q)
#pragma unroll
      for (int r = 0; r < 16; ++r)
        redbuf[(((w - 1) * 2 + q) * 16 + r) * 65 + lane] = acc2q[q][r];
  }
  __syncthreads();
  if (w == 0) {
#pragma unroll
    for (int q = 0; q < 2; ++q) {
      const int b = bg2 * 64 + q * 32 + l31;
      float* s1b = S1part + (((size_t)oc4 * 1024 + b) * 8 + d) * 32;
#pragma unroll
      for (int g = 0; g < 4; ++g) {
        f32x4 s = {acc2q[q][4 * g + 0], acc2q[q][4 * g + 1],
                   acc2q[q][4 * g + 2], acc2q[q][4 * g + 3]};
#pragma unroll
        for (int ww = 0; ww < 3; ++ww) {
          const float* rb = redbuf + ((ww * 2 + q) * 16) * 65 + lane;
          s[0] += rb[(4 * g + 0) * 65];
          s[1] += rb[(4 * g + 1) * 65];
          s[2] += rb[(4 * g + 2) * 65];
          s[3] += rb[(4 * g + 3) * 65];
        }
        *(f32x4*)(s1b + 8 * g + 4 * hi) = s;
      }
    }
  }

  // stats: per-wave shuffle reduction
#pragma unroll
  for (int off = 32; off; off >>= 1) {
    lsum += __shfl_down(lsum, off);
    lsq += __shfl_down(lsq, off);
  }
  if (lane == 0) {
    int slot = d * 256 + rest * 4 + w;
    spsum[slot] = lsum;
    spsq[slot] = lsq;
  }
}

#define W3S 33
#define W4S 99

__global__ __launch_bounds__(256) void k3_tail(
    const float* __restrict__ S1part, const float* __restrict__ spsum,
    const float* __restrict__ spsq, const float* __restrict__ wcsum,
    const float* __restrict__ bc, const float* __restrict__ b_mat,
    const float* __restrict__ h_mat, const float* __restrict__ a_mat,
    const float* __restrict__ noise, const float* __restrict__ indicator,
    const float* __restrict__ cutb, const float* __restrict__ W3,
    const float* __restrict__ b3, const float* __restrict__ W4,
    const float* __restrict__ b4, const float* __restrict__ Wo,
    const float* __restrict__ bo, float* __restrict__ out) {
  __shared__ float W3l[98 * W3S];
  __shared__ float W4l[49 * W4S];
  __shared__ float Wol[10 * 49];
  __shared__ float b3l[98], b4l[49], bol[10];
  __shared__ float cutl[32], coefl[256], konstl[32];
  __shared__ float mvals[8], vvals[8];
  __shared__ float sh_gm, sh_inv;
  __shared__ float offs[D_][J_];
  __shared__ float h1[8][32];
  __shared__ float h2[8][100];
  __shared__ float h3[8][52];
  __shared__ float lg[8][10];
  __shared__ float lsel[8];

  const int tid = threadIdx.x;

  for (int idx = tid; idx < 98 * 32; idx += 256) {
    int o = idx >> 5, j = idx & 31;
    W3l[o * W3S + j] = W3[idx];
  }
  for (int idx = tid; idx < 49 * 98; idx += 256) {
    int o = idx / 98, k = idx - o * 98;
    W4l[o * W4S + k] = W4[idx];
  }
  for (int idx = tid; idx < 490; idx += 256) Wol[idx] = Wo[idx];
  if (tid < 98) b3l[tid] = b3[tid];
  if (tid < 49) b4l[tid] = b4[tid];
  if (tid < 10) bol[tid] = bo[tid];
  if (tid < 32) cutl[tid] = cutb[tid];

  if (tid < 8) {
    float s = 0.0f, q = 0.0f;
    for (int i = 0; i < 256; ++i) {
      s += spsum[tid * 256 + i];
      q += spsq[tid * 256 + i];
    }
    const float inv_cnt = 1.0f / ((float)B_ * (float)NXT_);
    float m = s * inv_cnt;
    mvals[tid] = m;
    vvals[tid] = q * inv_cnt - m * m;
  }
  __syncthreads();
  if (tid == 0) {
    float gm = 0.0f, gv = 0.0f;
    for (int dd = 0; dd < 8; ++dd) {
      gm += mvals[dd];
      gv += vvals[dd];
    }
    gm *= 0.125f;
    gv *= 0.125f;
    sh_gm = gm;
    sh_inv = 1.0f / sqrtf(gv + 1e-6f);
  }
  __syncthreads();
  {
    int dd = tid >> 5, j = tid & 31;
    float hs[A_] = {0, 0, 0, 0, 0};
    for (int k = 0; k < K_; ++k) {
      float indv = indicator[j * K_ + k];
      if (indv != 0.0f) {
        const float* hp = h_mat + ((size_t)dd * K_ + k) * A_;
#pragma unroll
        for (int a = 0; a < A_; ++a) hs[a] = fmaf(indv, hp[a], hs[a]);
      }
    }
    float hv = 0.0f;
#pragma unroll
    for (int a = 0; a < A_; ++a) hv = fmaf(hs[a], a_mat[j * A_ + a], hv);
    float c = b_mat[dd * J_ + j] * hv;
    coefl[tid] = c * sh_inv;
    offs[dd][j] = c * (bc[dd * J_ + j] - sh_gm * wcsum[dd * J_ + j] * sh_inv);
  }
  __syncthreads();
  if (tid < J_) {
    float nz = 0.0f;
#pragma unroll
    for (int a = 0; a < A_; ++a)
      nz = fmaf(a_mat[tid * A_ + a], noise[tid * A_ + a], nz);
    float s = nz;
#pragma unroll
    for (int dd = 0; dd < D_; ++dd) s += offs[dd][tid];
    konstl[tid] = s;
  }
  __syncthreads();

  const int row = tid >> 5, lane = tid & 31;
  const int b = blockIdx.x * 8 + row;  // 125*8 = 1000 exactly

  float rsum = konstl[lane];
#pragma unroll
  for (int dd = 0; dd < D_; ++dd) {
    float s = 0.0f;
#pragma unroll
    for (int ocx = 0; ocx < 4; ++ocx)
      s += S1part[(((size_t)ocx * 1024 + b) * 8 + dd) * 32 + lane];
    rsum = fmaf(coefl[dd * J_ + lane], s, rsum);
  }
  h1[row][lane] = fmaxf(rsum + cutl[lane], 0.0f);
  __syncthreads();

  for (int o = lane; o < 98; o += 32) {
    float a = b3l[o];
#pragma unroll
    for (int j = 0; j < 32; ++j) a = fmaf(h1[row][j], W3l[o * W3S + j], a);
    h2[row][o] = fmaxf(a, 0.0f);
  }
  __syncthreads();

  for (int o = lane; o < 49; o += 32) {
    float a = b4l[o];
    for (int k = 0; k < 98; ++k) a = fmaf(h2[row][k], W4l[o * W4S + k], a);
    h3[row][o] = fmaxf(a, 0.0f);
  }
  __syncthreads();

  if (lane < 10) {
    float a = bol[lane];
#pragma unroll
    for (int k = 0; k < 49; ++k) a = fmaf(h3[row][k], Wol[lane * 49 + k], a);
    lg[row][lane] = a;
  }
  __syncthreads();
  if (lane == 0) {
    float mx = lg[row][0];
    for (int i = 1; i < 10; ++i) mx = fmaxf(mx, lg[row][i]);
    float se = 0.0f;
    for (int i = 0; i < 10; ++i) se += expf(lg[row][i] - mx);
    lsel[row] = mx + logf(se);
  }
  __syncthreads();
  if (lane < 10) out[(size_t)b * 10 + lane] = lg[row][lane] - lsel[row];
}

extern "C" void kernel_launch(void* const* d_in, const int* in_sizes, int n_in,
                              void* d_out, int out_size, void* d_ws,
                              size_t ws_size, hipStream_t stream) {
  const float* x = (const float*)d_in[0];
  const float* W1 = (const float*)d_in[1];
  const float* b1 = (const float*)d_in[2];
  const float* Wc = (const float*)d_in[3];
  const float* bc = (const float*)d_in[4];
  const float* cutb = (const float*)d_in[5];
  const float* bmat = (const float*)d_in[6];
  const float* hmat = (const float*)d_in[7];
  const float* amat = (const float*)d_in[8];
  const float* noise = (const float*)d_in[9];
  const float* W3 = (const float*)d_in[10];
  const float* b3 = (const float*)d_in[11];
  const float* W4 = (const float*)d_in[12];
  const float* b4 = (const float*)d_in[13];
  const float* Wo = (const float*)d_in[14];
  const float* bo = (const float*)d_in[15];
  const float* ind = (const float*)d_in[16];

  float* ws = (float*)d_ws;
  float* S1part = ws;                                      // [0, 1048576)
  unsigned short* w1a = (unsigned short*)(ws + 1048576);   // 2,097,152 us
  unsigned short* xa = (unsigned short*)(ws + 2097152);    // 1,048,576 us
  unsigned short* wca = (unsigned short*)(ws + 2621440);   // 524,288 us
  float* spsum = ws + 2883584;                             // 2048
  float* spsq = ws + 2885632;                              // 2048
  float* wcsum = ws + 2887680;                             // 256

  kcvt<<<2048, 256, 0, stream>>>(x, W1, b1, Wc, w1a, xa, wca, wcsum);
  k1_reg<<<512, 256, 0, stream>>>(w1a, xa, wca, S1part, spsum, spsq);
  k3_tail<<<125, 256, 0, stream>>>(S1part, spsum, spsq, wcsum, bc, bmat, hmat,
                                   amat, noise, ind, cutb, W3, b3, W4, b4, Wo,
                                   bo, (float*)d_out);
}